// Round 6
// baseline (342.671 us; speedup 1.0000x reference)
//
#include <hip/hip_runtime.h>

#define NC 8192
#define NT 4096
#define NLAGS 103
#define WS_STRIDE 104
#define XBASE (NC*NLAGS)

// ---------------- Kernel 1: per-channel cross-correlation ----------------
// One block (4 waves) per channel. Only d1s (zero-padded d1) lives in LDS;
// d2 is read from global (all 4 waves share the same range -> L1/L2 hits,
// HBM traffic unchanged).
// LDS layout: residue planes. logical granule q (16 B) -> phys granule
//   Q(q) = 144*(q&7) + (q>>3)         (bijective on [0,1152))
// Wave wv covers lags L = 32*wv + l - 1 (l=0..31); lane owns k in
// [2048*it + 32*lane, +32). Window base granule = 8*(lane + wv + 64*it)
// has residue 0, so EVERY w-read is   vb + literal   with
//   vb = d1b + 16*(lane + wv + 64*it),  literal = 2304*(t&7) + 16*(t>>3)
// -> zero per-read VALU, and fixed t gives phys = lane + const =
// 16B-consecutive across lanes = canonical conflict-free ds_read_b128.
// d1s logical dword x: [0,52) zero | [52,4148) g1[x-52] | [4148,4608) zero.
#define D1GR 1152            // 1052 logical granules padded to 144*8
#define SMEMDW (D1GR*4)      // 4608 dwords = 18 KB
#define REDS 33              // reduction row stride (odd: conflict-free)

#define OFFG(t) (2304*((t)&7) + 16*((t)>>3))

#define LOADB(OFF, B0,B1,B2,B3) do { \
    B0 = *(const float4*)(b0p + (OFF));      B1 = *(const float4*)(b0p + (OFF) + 4); \
    B2 = *(const float4*)(b0p + (OFF) + 8);  B3 = *(const float4*)(b0p + (OFF) + 12); \
} while(0)

// one k-half: j' in [0,16); w covers window dwords [16H, 16H+47]
#define PHASE(VB, H, C0,C1,C2,C3) do { \
    float w[48]; \
    _Pragma("unroll") \
    for (int t = 0; t < 12; ++t) { \
        float4 v = *(const float4*)((VB) + OFFG(4*(H) + t)); \
        w[4*t+0]=v.x; w[4*t+1]=v.y; w[4*t+2]=v.z; w[4*t+3]=v.w; \
    } \
    float b[16]; \
    b[0]=C0.x; b[1]=C0.y; b[2]=C0.z; b[3]=C0.w; \
    b[4]=C1.x; b[5]=C1.y; b[6]=C1.z; b[7]=C1.w; \
    b[8]=C2.x; b[9]=C2.y; b[10]=C2.z; b[11]=C2.w; \
    b[12]=C3.x; b[13]=C3.y; b[14]=C3.z; b[15]=C3.w; \
    _Pragma("unroll") \
    for (int j = 0; j < 16; ++j) \
        _Pragma("unroll") \
        for (int l = 0; l < 32; ++l) \
            acc[l] = fmaf(w[l+j], b[j], acc[l]); \
} while(0)

__global__ __launch_bounds__(256, 4)
void xcorr_kernel(const float* __restrict__ g1, const float* __restrict__ g2,
                  float* __restrict__ ws) {
    __shared__ __align__(16) float smem[SMEMDW];
    char* d1b = (char*)smem;
    const int tid  = threadIdx.x;
    const int wv   = tid >> 6;
    const int lane = tid & 63;
    const int c    = blockIdx.x;
    const float* g1c = g1 + (size_t)c * NT;
    const float* g2c = g2 + (size_t)c * NT;
    const float* b0p = g2c + 32*lane;        // this lane's d2 dword base

    // phase (0,0) d2 prefetch — oldest in the vmem queue
    float4 Ba0,Ba1,Ba2,Ba3, Bb0,Bb1,Bb2,Bb3;
    LOADB(0, Ba0,Ba1,Ba2,Ba3);

    // ---- stage d1s: phys-linear conflict-free writes, Qinv-gathered src ----
    #pragma unroll
    for (int s = 0; s < 5; ++s) {
        const int p = tid + 256*s;
        if (p < D1GR) {
            const int q = 8*(p % 144) + (p / 144);     // Qinv(p)
            float4 v = make_float4(0.f, 0.f, 0.f, 0.f);
            if (q >= 13 && q < 1037)                   // data granules
                v = *(const float4*)((const char*)g1c + 16*q - 208);
            *(float4*)(d1b + 16*p) = v;
        }
    }
    __syncthreads();   // d1 staged (drains gathers + ds_writes; Ba also ready)

    float acc[32];
    #pragma unroll
    for (int l = 0; l < 32; ++l) acc[l] = 0.f;

    const char* vb0 = d1b + 16*(lane + wv);            // it=0 window base
    const char* vb1 = vb0 + 1024;                      // it=1 (+16*64)

    LOADB(16,   Bb0,Bb1,Bb2,Bb3);                      // (0,1) prefetch
    PHASE(vb0, 0, Ba0,Ba1,Ba2,Ba3);
    LOADB(2048, Ba0,Ba1,Ba2,Ba3);                      // (1,0) prefetch
    PHASE(vb0, 1, Bb0,Bb1,Bb2,Bb3);
    LOADB(2064, Bb0,Bb1,Bb2,Bb3);                      // (1,1) prefetch
    PHASE(vb1, 0, Ba0,Ba1,Ba2,Ba3);
    PHASE(vb1, 1, Bb0,Bb1,Bb2,Bb3);

    // ---- cross-lane reduction; d1 LDS is dead after this barrier ----
    __syncthreads();
    #pragma unroll
    for (int l = 0; l < 32; ++l) acc[l] += __shfl_down(acc[l], 32);
    float* red = smem + wv * (32*REDS);                // 4*1056 = 4224 <= 4608
    if (lane < 32) {
        #pragma unroll
        for (int l = 0; l < 32; ++l) red[lane*REDS + l] = acc[l];
        // same-wave DS ordering: no barrier before read-back
        float s = 0.f;
        #pragma unroll
        for (int r = 0; r < 32; ++r) s += red[r*REDS + lane];
        const int L = 32*wv + lane - 1;
        if (L >= 0 && L < NLAGS) ws[(size_t)c * WS_STRIDE + L] = s;
    }
}

// -------- Kernel 2: moving average across channels + pick max|R| --------
#define TS 112   // tile stride (16*7: rows alias 2-way = free)
__global__ __launch_bounds__(256, 4)
void ma_pick_kernel(const float* __restrict__ ws, float* __restrict__ out) {
    __shared__ float tile[52*TS];
    __shared__ float matile[32*TS];
    const int tid = threadIdx.x;
    const int c0  = blockIdx.x * 32;

    for (int i = tid; i < 52*TS; i += 256) {
        int r   = i / TS;
        int col = i - r*TS;
        int g   = c0 - 10 + r;
        float v = 0.f;
        if (g >= 0 && g < NC && col < NLAGS) v = ws[(size_t)g*WS_STRIDE + col];
        tile[i] = v;
    }
    __syncthreads();

    {   // rolling 20-channel window sum; thread = one lag, 16 channels
        const int l = tid & 127;
        const int h = tid >> 7;
        if (l < NLAGS) {
            const int cc0 = h * 16;
            float s = 0.f;
            #pragma unroll
            for (int r = 0; r < 20; ++r) s += tile[(cc0 + r)*TS + l];
            #pragma unroll 1
            for (int cc = cc0; cc < cc0 + 16; ++cc) {
                float ma = s / 20.0f;
                matile[cc*TS + l] = ma;
                out[(size_t)(c0 + cc)*NLAGS + l] = ma;   // coalesced across l
                s += tile[(cc + 20)*TS + l] - tile[cc*TS + l];
            }
        }
    }
    __syncthreads();

    // per-channel argmax|R| (first-index tie-break), max, min
    const int wv = tid >> 6, lane = tid & 63;
    #pragma unroll 1
    for (int s8 = 0; s8 < 8; ++s8) {
        const int cc = wv*8 + s8;
        float v1 = matile[cc*TS + lane];
        float a1 = fabsf(v1);
        int   i1 = lane;
        float vmx = v1, vmn = v1;
        if (lane < NLAGS - 64) {                 // second element: l = lane+64
            float v2 = matile[cc*TS + 64 + lane];
            float a2 = fabsf(v2);
            vmx = fmaxf(vmx, v2); vmn = fminf(vmn, v2);
            if (a2 > a1) { a1 = a2; i1 = 64 + lane; v1 = v2; }
        }
        #pragma unroll
        for (int d = 32; d >= 1; d >>= 1) {
            float oa  = __shfl_xor(a1, d);
            int   oi  = __shfl_xor(i1, d);
            float ov  = __shfl_xor(v1, d);
            float omx = __shfl_xor(vmx, d);
            float omn = __shfl_xor(vmn, d);
            vmx = fmaxf(vmx, omx);
            vmn = fminf(vmn, omn);
            if (oa > a1 || (oa == a1 && oi < i1)) { a1 = oa; i1 = oi; v1 = ov; }
        }
        if (lane == 0) {
            const int ch = c0 + cc;
            out[XBASE + ch]        = v1;                         // vmain
            out[XBASE + NC + ch]   = (v1 >= 0.f) ? vmn : vmx;    // vside
            out[XBASE + 2*NC + ch] = (float)(i1 - 51) * 0.01f;   // tmax
        }
    }
}

extern "C" void kernel_launch(void* const* d_in, const int* in_sizes, int n_in,
                              void* d_out, int out_size, void* d_ws, size_t ws_size,
                              hipStream_t stream) {
    const float* g1 = (const float*)d_in[0];
    const float* g2 = (const float*)d_in[1];
    float* out = (float*)d_out;
    float* ws  = (float*)d_ws;   // 8192*104*4 = 3.4 MB scratch

    hipLaunchKernelGGL(xcorr_kernel, dim3(NC), dim3(256), 0, stream, g1, g2, ws);
    hipLaunchKernelGGL(ma_pick_kernel, dim3(NC/32), dim3(256), 0, stream, ws, out);
}